// Round 3
// baseline (88.657 us; speedup 1.0000x reference)
//
#include <hip/hip_runtime.h>
#include <stdint.h>

#define S 2048
#define DHEAD 64
#define CDIM 256
#define NBATCH 8

typedef __attribute__((ext_vector_type(4))) float f32x4;
typedef __attribute__((ext_vector_type(8))) short s16x8;
typedef __attribute__((ext_vector_type(8))) _Float16 f16x8;
typedef __attribute__((ext_vector_type(4))) unsigned short u16x4;

static __device__ __forceinline__ unsigned short f2bf(float f) {
    unsigned int u = __builtin_bit_cast(unsigned int, f);
    unsigned int r = (u + 0x7FFFu + ((u >> 16) & 1u)) >> 16;  // RNE
    return (unsigned short)r;
}
static __device__ __forceinline__ unsigned short f2h(float f) {
    _Float16 h = (_Float16)f;
    return __builtin_bit_cast(unsigned short, h);
}

// ---------------- kernel 0: a (fp32) -> a16 (bf16) ----------------
__global__ __launch_bounds__(256) void cvt_a_kernel(const float* __restrict__ a,
                                                    unsigned short* __restrict__ a16,
                                                    int n4) {
    int i = blockIdx.x * 256 + threadIdx.x;
    int stride = gridDim.x * 256;
    for (; i < n4; i += stride) {
        f32x4 v = ((const f32x4*)a)[i];
        u16x4 o;
        o.x = f2bf(v.x); o.y = f2bf(v.y); o.z = f2bf(v.z); o.w = f2bf(v.w);
        ((u16x4*)a16)[i] = o;
    }
}

// ---------------- fused kernel ----------------
// One block (512 thr, 8 waves) owns n-tile of 64 out-columns x all 256 c-rows
// for one batch. Iterates 16 m-tiles (128 m each):
//   scores: s[128m][64n] = c-tile (f16) x b-tile (f16) MFMA  (R2-verified layout)
//   E-tile = exp(s) -> bf16 in LDS [64n][128m+pad]; L accumulated in regs
//   PV: acc[c][n] += a16[c][m-tile] (global/L2) x E-tile^T   (R2-verified layout)
// Epilogue: out = acc / L + a.
__global__ __launch_bounds__(512) void fused_kernel(
    const float* __restrict__ Bq, const float* __restrict__ Ck,
    const unsigned short* __restrict__ a16, const float* __restrict__ afull,
    float* __restrict__ out)
{
    // XCD-chunked bijective swizzle: 256 blocks, 8 XCDs, 32 blocks each ->
    // one batch per XCD (a16/b/c of that batch stay L2-resident).
    const int bid = blockIdx.x;
    const int swz = (bid & 7) * 32 + (bid >> 3);
    const int gb = swz >> 5;   // batch
    const int nt = swz & 31;   // n-tile
    const int n0 = nt * 64;

    const float* __restrict__ bp = Bq + (size_t)gb * S * DHEAD;
    const float* __restrict__ cp = Ck + (size_t)gb * S * DHEAD;
    const unsigned short* __restrict__ ap16 = a16 + (size_t)gb * CDIM * S;
    const float* __restrict__ ap = afull + (size_t)gb * CDIM * S;
    float* __restrict__ op = out + (size_t)gb * CDIM * S;

    __shared__ unsigned short bs[64 * 72];    // f16, b rows (n), pad 72
    __shared__ unsigned short cs[128 * 72];   // f16, c rows (m), pad 72
    __shared__ unsigned short es[64 * 136];   // bf16 E-tile [n][m], pad 136
    __shared__ float Lsh[8 * 16];

    const int tid = threadIdx.x;
    const int lane = tid & 63;
    const int w = tid >> 6;
    const int q = lane >> 4, r15 = lane & 15;
    const int ncol = w & 3, mh = w >> 2;      // scores roles: n-frag col, m-half
    const int wr = w >> 1, wn = w & 1;        // PV roles: c 64-group, n 32-group

    // stage b-tile once: rows n0..n0+63, fp32 -> f16
    #pragma unroll
    for (int t = 0; t < 2; ++t) {
        int ch = tid + 512 * t;
        int row = ch >> 4, c4 = ch & 15;
        f32x4 v = *(const f32x4*)&bp[(size_t)(n0 + row) * DHEAD + c4 * 4];
        u16x4 o;
        o.x = f2h(v.x); o.y = f2h(v.y); o.z = f2h(v.z); o.w = f2h(v.w);
        *(u16x4*)&bs[row * 72 + c4 * 4] = o;
    }

    f32x4 acc[4][2] = {};
    float Lrun = 0.f;

    for (int mt = 0; mt < 16; ++mt) {
        const int m0 = mt * 128;

        // stage c-tile: rows m0..m0+127, fp32 -> f16 (reg-staged)
        f32x4 cv[4];
        #pragma unroll
        for (int t = 0; t < 4; ++t) {
            int ch = tid + 512 * t;
            int row = ch >> 4, c4 = ch & 15;
            cv[t] = *(const f32x4*)&cp[(size_t)(m0 + row) * DHEAD + c4 * 4];
        }
        #pragma unroll
        for (int t = 0; t < 4; ++t) {
            int ch = tid + 512 * t;
            int row = ch >> 4, c4 = ch & 15;
            u16x4 o;
            o.x = f2h(cv[t].x); o.y = f2h(cv[t].y);
            o.z = f2h(cv[t].z); o.w = f2h(cv[t].w);
            *(u16x4*)&cs[row * 72 + c4 * 4] = o;
        }
        __syncthreads();  // B1: cs visible; prior PV es-reads complete

        // scores: wave covers m-half (64 rows) x n-col (16): 4x1 frags, K=64
        f32x4 sacc[4] = {};
        #pragma unroll
        for (int kk = 0; kk < 2; ++kk) {
            f16x8 bfr = *(const f16x8*)&bs[(ncol * 16 + r15) * 72 + kk * 32 + q * 8];
            #pragma unroll
            for (int i = 0; i < 4; ++i) {
                f16x8 afr = *(const f16x8*)&cs[(mh * 64 + i * 16 + r15) * 72 + kk * 32 + q * 8];
                sacc[i] = __builtin_amdgcn_mfma_f32_16x16x32_f16(afr, bfr, sacc[i], 0, 0, 0);
            }
        }

        // exp + pack + write E-tile [n][m]; accumulate row sums
        #pragma unroll
        for (int i = 0; i < 4; ++i) {
            float e0 = __expf(sacc[i][0]);
            float e1 = __expf(sacc[i][1]);
            float e2 = __expf(sacc[i][2]);
            float e3 = __expf(sacc[i][3]);
            Lrun += (e0 + e1) + (e2 + e3);
            u16x4 pk;
            pk.x = f2bf(e0); pk.y = f2bf(e1); pk.z = f2bf(e2); pk.w = f2bf(e3);
            *(u16x4*)&es[(ncol * 16 + r15) * 136 + mh * 64 + i * 16 + q * 4] = pk;
        }

        // prefetch PV A-frags for ks=0 (global/L2; consumed after B2)
        s16x8 afc[4];
        #pragma unroll
        for (int i = 0; i < 4; ++i)
            afc[i] = *(const s16x8*)&ap16[(size_t)(wr * 64 + i * 16 + r15) * S + m0 + q * 8];

        __syncthreads();  // B2: es visible

        // PV: acc[c 64-group][n 32-group] += a16-tile x E-tile^T, K=128 (4 ks)
        #pragma unroll
        for (int ks = 0; ks < 4; ++ks) {
            s16x8 afn[4];
            if (ks < 3) {
                #pragma unroll
                for (int i = 0; i < 4; ++i)
                    afn[i] = *(const s16x8*)&ap16[(size_t)(wr * 64 + i * 16 + r15) * S + m0 + (ks + 1) * 32 + q * 8];
            }
            s16x8 bfr[2];
            #pragma unroll
            for (int j = 0; j < 2; ++j)
                bfr[j] = *(const s16x8*)&es[(wn * 32 + j * 16 + r15) * 136 + ks * 32 + q * 8];
            #pragma unroll
            for (int i = 0; i < 4; ++i)
                #pragma unroll
                for (int j = 0; j < 2; ++j)
                    acc[i][j] = __builtin_amdgcn_mfma_f32_16x16x32_bf16(afc[i], bfr[j], acc[i][j], 0, 0, 0);
            #pragma unroll
            for (int i = 0; i < 4; ++i) afc[i] = afn[i];
        }
    }

    // reduce L: lane holds partial for n = ncol*16 + r15 (over its m/q subset)
    Lrun += __shfl_xor(Lrun, 16);
    Lrun += __shfl_xor(Lrun, 32);
    if (lane < 16) Lsh[w * 16 + lane] = Lrun;
    __syncthreads();

    // epilogue: out = acc / L + a
    float rcpL[2];
    #pragma unroll
    for (int j = 0; j < 2; ++j) {
        int nloc = wn * 32 + j * 16 + r15;
        float Lv = Lsh[(nloc >> 4) * 16 + (nloc & 15)] + Lsh[(4 + (nloc >> 4)) * 16 + (nloc & 15)];
        rcpL[j] = 1.0f / Lv;
    }
    #pragma unroll
    for (int i = 0; i < 4; ++i) {
        #pragma unroll
        for (int rr = 0; rr < 4; ++rr) {
            int cc = wr * 64 + i * 16 + q * 4 + rr;
            size_t base = (size_t)cc * S + n0;
            #pragma unroll
            for (int j = 0; j < 2; ++j) {
                int nloc = wn * 32 + j * 16 + r15;
                op[base + nloc] = acc[i][j][rr] * rcpL[j] + ap[base + nloc];
            }
        }
    }
}

// ---------------- launch ----------------
extern "C" void kernel_launch(void* const* d_in, const int* in_sizes, int n_in,
                              void* d_out, int out_size, void* d_ws, size_t ws_size,
                              hipStream_t stream) {
    const float* a = (const float*)d_in[0];
    const float* b = (const float*)d_in[1];
    const float* c = (const float*)d_in[2];
    float* out = (float*)d_out;

    unsigned short* a16 = (unsigned short*)d_ws;  // 8 MB

    cvt_a_kernel<<<1024, 256, 0, stream>>>(a, a16, NBATCH * CDIM * S / 4);
    fused_kernel<<<256, 512, 0, stream>>>(b, c, a16, a, out);
}